// Round 11
// baseline (159.631 us; speedup 1.0000x reference)
//
#include <hip/hip_runtime.h>
#include <stdint.h>

// Problem constants: n_class=32, n_support=16, n_query=16, D=1024;
// query rows Q = 512. Output (512, 32, 1024) fp32.
constexpr int NC = 32, NS = 16, NQ = 512, D = 1024;
constexpr int QPB = 8;     // queries per block = 4 waves x 2 queries/wave

// clang ext-vectors -> VOP3P packed fp32 (v_pk_fma_f32 etc., full-rate 2xf32)
typedef float v2f __attribute__((ext_vector_type(2)));
typedef float v4f __attribute__((ext_vector_type(4)));

// Packed quad accumulate (round-7 proven): acc += f(t0)+f(t1)+f(t2)+f(t3),
// f(t)=1/(exp2(t)+1), 2 rcp per 4 elements, packed full-rate ops.
// No clamp (validated rounds 3..10): exp2 can't overflow individually for
// this data; if A*B -> inf, rcp -> 0, contribution 0 (truth ~2^-100);
// A+B stays finite so no NaN.
__device__ __forceinline__ void quad_acc(v2f t01, v2f t23, float& acc) {
    v2f A, B;
    A.x = __builtin_amdgcn_exp2f(t01.x);
    A.y = __builtin_amdgcn_exp2f(t01.y);
    B.x = __builtin_amdgcn_exp2f(t23.x);
    B.y = __builtin_amdgcn_exp2f(t23.y);
    A += 1.f;                  // v_pk_add
    B += 1.f;
    v2f prod = A * B;          // v_pk_mul
    v2f sum  = A + B;          // v_pk_add
    acc = fmaf(sum.x, __builtin_amdgcn_rcpf(prod.x), acc);
    acc = fmaf(sum.y, __builtin_amdgcn_rcpf(prod.y), acc);
}

// Direct global->LDS DMA, 16B/lane, zero VGPR round-trip (round-8 proven).
// LDS dest = wave-uniform base + lane*16 (linear); one call = 256 floats.
__device__ __forceinline__ void gload_lds16(const float* g, float* l) {
    __builtin_amdgcn_global_load_lds(
        (const __attribute__((address_space(1))) void*)g,
        (__attribute__((address_space(3))) void*)l,
        16, 0, 0);
}

// Round-11: round-10's 2-barrier schedule, spills removed.
//   stage h0 (DMA) ; bar0 ; { stage h1 under score-h0 } ; bar1 ; score-h1 ;
//   then BARRIER-FREE to exit: reduction, softmax, proto from resident LDS.
// launch_bounds(256) [min-waves=1 -> VGPR cap 512]: with 64 KB LDS the
// occupancy is LDS-capped at 2 blocks/CU = 2 waves/SIMD REGARDLESS of VGPR
// up to 256 — so the old (256,2) 128-cap only forced ~40 MB of scratch
// traffic (round 10: WRITE_SIZE 105.9 MB, VGPR pinned at 128). Let the
// allocator take ~150 regs. Tripwire: WRITE_SIZE == 65536 KB exactly.
__global__ __launch_bounds__(256)
void proto_attn_kernel(const float* __restrict__ data, float* __restrict__ out) {
    const int c    = blockIdx.x;   // class
    const int qt   = blockIdx.y;   // query tile
    const int tid  = threadIdx.x;
    const int wave = tid >> 6;
    const int lane = tid & 63;

    // Both d-halves of support[c] resident: 2 x (16 rows x 512 floats) = 64 KB.
    __shared__ __align__(16) float buf[2][NS * 512];

    const float* sup = data + (size_t)c * NS * D;

    // async-stage half h: per wave 4 rows x 2 DMAs (8 instrs, 0 VGPR).
    auto stage = [&](int h) {
        #pragma unroll
        for (int r = 0; r < 4; ++r) {
            int row = 4 * wave + r;
            const float* g = sup + row * D + h * 512 + lane * 4;
            gload_lds16(g,       &buf[h][row * 512]);
            gload_lds16(g + 256, &buf[h][row * 512 + 256]);
        }
    };

    const float K = 2.88539008177792681472f;   // 2*log2(e); tanh(x)=1-2/(exp2(Kx)+1)
    const int q0 = qt * QPB + wave * 2;
    const v4f* qg0 = reinterpret_cast<const v4f*>(data + (size_t)(NC * NS + q0) * D);
    const v4f* qg1 = qg0 + 256;   // next query row

    stage(0);   // prologue DMA; retires under the query loads below

    // queries, all 4 d-quarters, pre-scaled by K (32 VGPR, held)
    v4f qa[4], qb[4];
    #pragma unroll
    for (int j = 0; j < 4; ++j) {
        qa[j] = qg0[64 * j + lane] * K;
        qb[j] = qg1[64 * j + lane] * K;
    }
    __syncthreads();   // bar0: vmcnt drain -> h0 staged & visible

    float sc0[NS], sc1[NS];
    #pragma unroll
    for (int s = 0; s < NS; ++s) { sc0[s] = 0.f; sc1[s] = 0.f; }

    stage(1);   // DMA h1 into the other half; covered by ~1400cy score-h0

    // ---- score over h0 ----
    {
        const v4f* B = reinterpret_cast<const v4f*>(buf[0]);
        #pragma unroll
        for (int s = 0; s < NS; ++s) {
            #pragma unroll
            for (int j = 0; j < 2; ++j) {
                v4f sv = B[(s << 7) + (j << 6) + lane];
                quad_acc(sv.xy * qa[j].xy, sv.zw * qa[j].zw, sc0[s]);
                quad_acc(sv.xy * qb[j].xy, sv.zw * qb[j].zw, sc1[s]);
            }
        }
    }
    __syncthreads();   // bar1: vmcnt drain -> h1 staged & visible

    // ---- score over h1 ----  (LAST barrier; free-run from here to exit)
    {
        const v4f* B = reinterpret_cast<const v4f*>(buf[1]);
        #pragma unroll
        for (int s = 0; s < NS; ++s) {
            #pragma unroll
            for (int j = 0; j < 2; ++j) {
                v4f sv = B[(s << 7) + (j << 6) + lane];
                quad_acc(sv.xy * qa[2 + j].xy, sv.zw * qa[2 + j].zw, sc0[s]);
                quad_acc(sv.xy * qb[2 + j].xy, sv.zw * qb[2 + j].zw, sc1[s]);
            }
        }
    }

    // ---- wave64 butterfly reduction: sc[q][s] = D - 2*sum_d f ----
    #pragma unroll
    for (int s = 0; s < NS; ++s) {
        float r0 = sc0[s], r1 = sc1[s];
        #pragma unroll
        for (int m = 32; m >= 1; m >>= 1) {
            r0 += __shfl_xor(r0, m, 64);
            r1 += __shfl_xor(r1, m, 64);
        }
        sc0[s] = (float)D - 2.f * r0;
        sc1[s] = (float)D - 2.f * r1;
    }

    // ---- softmax over s (16 values, replicated per lane) ----
    const float L2E = 1.44269504088896340736f;
    float m0 = sc0[0], m1 = sc1[0];
    #pragma unroll
    for (int s = 1; s < NS; ++s) { m0 = fmaxf(m0, sc0[s]); m1 = fmaxf(m1, sc1[s]); }
    float sum0 = 0.f, sum1 = 0.f;
    #pragma unroll
    for (int s = 0; s < NS; ++s) {
        sc0[s] = __builtin_amdgcn_exp2f((sc0[s] - m0) * L2E);
        sc1[s] = __builtin_amdgcn_exp2f((sc1[s] - m1) * L2E);
        sum0 += sc0[s];
        sum1 += sc1[s];
    }
    const float inv0 = __builtin_amdgcn_rcpf(sum0);
    const float inv1 = __builtin_amdgcn_rcpf(sum1);
    #pragma unroll
    for (int s = 0; s < NS; ++s) { sc0[s] *= inv0; sc1[s] *= inv1; }

    v4f* og0 = reinterpret_cast<v4f*>(out + ((size_t)q0 * NC + c) * D);
    v4f* og1 = reinterpret_cast<v4f*>(out + ((size_t)(q0 + 1) * NC + c) * D);

    // ---- proto from resident LDS (both halves), packed FMAs, no barriers ----
    #pragma unroll
    for (int p = 0; p < 4; ++p) {
        const v4f* B = reinterpret_cast<const v4f*>(buf[p >> 1]);
        const int jo = (p & 1) << 6;
        v2f oxy0 = 0.f, ozw0 = 0.f, oxy1 = 0.f, ozw1 = 0.f;
        #pragma unroll
        for (int s = 0; s < NS; ++s) {
            v4f sv = B[(s << 7) + jo + lane];
            oxy0 += sv.xy * sc0[s];   // v_pk_fma_f32
            ozw0 += sv.zw * sc0[s];
            oxy1 += sv.xy * sc1[s];
            ozw1 += sv.zw * sc1[s];
        }
        v4f r0, r1;
        r0.xy = oxy0; r0.zw = ozw0;
        r1.xy = oxy1; r1.zw = ozw1;
        og0[(p << 6) + lane] = r0;
        og1[(p << 6) + lane] = r1;
    }
}

extern "C" void kernel_launch(void* const* d_in, const int* in_sizes, int n_in,
                              void* d_out, int out_size, void* d_ws, size_t ws_size,
                              hipStream_t stream) {
    (void)in_sizes; (void)n_in; (void)out_size; (void)d_ws; (void)ws_size;
    const float* data = (const float*)d_in[0];
    float* out = (float*)d_out;
    dim3 grid(NC, NQ / QPB);   // 32 classes x 64 query tiles = 2048 blocks
    proto_attn_kernel<<<grid, dim3(256), 0, stream>>>(data, out);
}

// Round 12
// 141.718 us; speedup vs baseline: 1.1264x; 1.1264x over previous
//
#include <hip/hip_runtime.h>
#include <stdint.h>

// Problem constants: n_class=32, n_support=16, n_query=16, D=1024;
// query rows Q = 512. Output (512, 32, 1024) fp32.
constexpr int NC = 32, NS = 16, NQ = 512, D = 1024;
constexpr int QPB = 16;    // queries per block = 4 waves x 4 queries/wave
constexpr int NQW = 4;     // queries per wave

// clang ext-vectors -> VOP3P packed fp32 (v_pk_fma_f32 etc., full-rate 2xf32)
typedef float v2f __attribute__((ext_vector_type(2)));
typedef float v4f __attribute__((ext_vector_type(4)));

// Packed quad accumulate (round-7 proven): acc += f(t0)+f(t1)+f(t2)+f(t3),
// f(t)=1/(exp2(t)+1), 2 rcp per 4 elements, packed full-rate ops.
// No clamp (validated rounds 3..11): exp2 can't overflow individually for
// this data; if A*B -> inf, rcp -> 0, contribution 0 (truth ~2^-100);
// A+B stays finite so no NaN.
__device__ __forceinline__ void quad_acc(v2f t01, v2f t23, float& acc) {
    v2f A, B;
    A.x = __builtin_amdgcn_exp2f(t01.x);
    A.y = __builtin_amdgcn_exp2f(t01.y);
    B.x = __builtin_amdgcn_exp2f(t23.x);
    B.y = __builtin_amdgcn_exp2f(t23.y);
    A += 1.f;                  // v_pk_add
    B += 1.f;
    v2f prod = A * B;          // v_pk_mul
    v2f sum  = A + B;          // v_pk_add
    acc = fmaf(sum.x, __builtin_amdgcn_rcpf(prod.x), acc);
    acc = fmaf(sum.y, __builtin_amdgcn_rcpf(prod.y), acc);
}

// Direct global->LDS DMA, 16B/lane, zero VGPR round-trip (round-8 proven).
// LDS dest = wave-uniform base + lane*16 (linear); one call = 256 floats.
__device__ __forceinline__ void gload_lds16(const float* g, float* l) {
    __builtin_amdgcn_global_load_lds(
        (const __attribute__((address_space(1))) void*)g,
        (__attribute__((address_space(3))) void*)l,
        16, 0, 0);
}

// Round-12: QPB=16 (4 q/wave). 1024 blocks; 32 KB LDS quarter double-buffer
// (R8's proven score pipeline, phases now ~2x fatter); proto from resident
// LDS: quarters 2,3 are still in the buffers when score ends (0 barriers),
// one restage round for quarters 0,1 (2 barriers). 6 barriers/block over
// half as many blocks. Support staged once per 16 queries (was 8).
// launch_bounds(256,2): this kernel MUST live in the <=128-VGPR /
// 4-waves-per-SIMD bucket — cap 64 spills (R1/R5), uncapped >128 halves
// wave slots and lost 28us (R11). Tripwire: WRITE_SIZE == 65536 KB exactly.
__global__ __launch_bounds__(256, 2)
void proto_attn_kernel(const float* __restrict__ data, float* __restrict__ out) {
    const int c    = blockIdx.x;   // class
    const int qt   = blockIdx.y;   // query tile (of 16 queries)
    const int tid  = threadIdx.x;
    const int wave = tid >> 6;
    const int lane = tid & 63;

    // Double-buffered d-quarter of support[c]: 2 x (16 rows x 256 floats) = 32 KB.
    __shared__ __align__(16) float buf[2][NS * 256];

    const float* sup = data + (size_t)c * NS * D;

    // async-stage quarter p into buf[b]: per wave 4 rows, 1 DMA each (0 VGPR).
    auto stage = [&](int p, int b) {
        #pragma unroll
        for (int r = 0; r < 4; ++r) {
            int row = 4 * wave + r;
            gload_lds16(sup + row * D + p * 256 + lane * 4,
                        &buf[b][row * 256]);
        }
    };

    const float K = 2.88539008177792681472f;   // 2*log2(e); tanh(x)=1-2/(exp2(Kx)+1)
    const int q0 = qt * QPB + wave * NQW;
    const v4f* qg = reinterpret_cast<const v4f*>(data + (size_t)(NC * NS + q0) * D);
    // query row r lives at qg + r*256 (v4f units)

    stage(0, 0);       // prologue DMA
    __syncthreads();   // vmcnt drain -> quarter 0 staged

    float sc[NQW][NS];
    #pragma unroll
    for (int r = 0; r < NQW; ++r)
        #pragma unroll
        for (int s = 0; s < NS; ++s) sc[r][s] = 0.f;

    // ---- score phases p=0..3: DMA next quarter into other buffer, compute
    //      current (~2x fatter than R8: 4 queries share each LDS read).
    //      Queries loaded per-phase (16 regs live) — keeps sc[64] affordable.
    #pragma unroll
    for (int p = 0; p < 4; ++p) {
        if (p < 3) stage(p + 1, (p + 1) & 1);
        v4f q[NQW];
        #pragma unroll
        for (int r = 0; r < NQW; ++r)
            q[r] = qg[r * 256 + (p << 6) + lane] * K;
        const v4f* B = reinterpret_cast<const v4f*>(buf[p & 1]);
        #pragma unroll
        for (int s = 0; s < NS; ++s) {
            v4f sv = B[(s << 6) + lane];
            #pragma unroll
            for (int r = 0; r < NQW; ++r)
                quad_acc(sv.xy * q[r].xy, sv.zw * q[r].zw, sc[r][s]);
        }
        if (p < 3) __syncthreads();
    }
    // After score: buf0 = quarter 2, buf1 = quarter 3 (still resident).

    // ---- wave64 butterfly reduction: sc = D - 2*sum_d f (barrier-free) ----
    #pragma unroll
    for (int r = 0; r < NQW; ++r)
        #pragma unroll
        for (int s = 0; s < NS; ++s) {
            float v = sc[r][s];
            #pragma unroll
            for (int m = 32; m >= 1; m >>= 1) v += __shfl_xor(v, m, 64);
            sc[r][s] = (float)D - 2.f * v;
        }

    // ---- softmax over s per query (replicated per lane) ----
    const float L2E = 1.44269504088896340736f;
    #pragma unroll
    for (int r = 0; r < NQW; ++r) {
        float mx = sc[r][0];
        #pragma unroll
        for (int s = 1; s < NS; ++s) mx = fmaxf(mx, sc[r][s]);
        float sum = 0.f;
        #pragma unroll
        for (int s = 0; s < NS; ++s) {
            sc[r][s] = __builtin_amdgcn_exp2f((sc[r][s] - mx) * L2E);
            sum += sc[r][s];
        }
        const float inv = __builtin_amdgcn_rcpf(sum);
        #pragma unroll
        for (int s = 0; s < NS; ++s) sc[r][s] *= inv;
    }

    // ---- proto for one d-quarter qq from buf[b]: 16 LDS reads shared by
    //      4 queries, 8 v2f accumulators (16 regs), packed FMAs ----
    auto proto_quarter = [&](int qq, int b) {
        const v4f* B = reinterpret_cast<const v4f*>(buf[b]);
        v2f oxy[NQW], ozw[NQW];
        #pragma unroll
        for (int r = 0; r < NQW; ++r) { oxy[r] = 0.f; ozw[r] = 0.f; }
        #pragma unroll
        for (int s = 0; s < NS; ++s) {
            v4f sv = B[(s << 6) + lane];
            #pragma unroll
            for (int r = 0; r < NQW; ++r) {
                oxy[r] += sv.xy * sc[r][s];   // v_pk_fma_f32
                ozw[r] += sv.zw * sc[r][s];
            }
        }
        #pragma unroll
        for (int r = 0; r < NQW; ++r) {
            v4f o; o.xy = oxy[r]; o.zw = ozw[r];
            v4f* og = reinterpret_cast<v4f*>(out + ((size_t)(q0 + r) * NC + c) * D);
            og[(qq << 6) + lane] = o;
        }
    };

    // quarters 2,3 straight from the still-resident buffers — no barrier
    proto_quarter(2, 0);
    proto_quarter(3, 1);
    __syncthreads();           // all waves done reading buf
    stage(0, 0);               // restage quarters 0,1 (L2-hot DMA)
    stage(1, 1);
    __syncthreads();           // DMA drain
    proto_quarter(0, 0);
    proto_quarter(1, 1);
}

extern "C" void kernel_launch(void* const* d_in, const int* in_sizes, int n_in,
                              void* d_out, int out_size, void* d_ws, size_t ws_size,
                              hipStream_t stream) {
    (void)in_sizes; (void)n_in; (void)out_size; (void)d_ws; (void)ws_size;
    const float* data = (const float*)d_in[0];
    float* out = (float*)d_out;
    dim3 grid(NC, NQ / QPB);   // 32 classes x 32 query tiles = 1024 blocks
    proto_attn_kernel<<<grid, dim3(256), 0, stream>>>(data, out);
}

// Round 13
// 131.102 us; speedup vs baseline: 1.2176x; 1.0810x over previous
//
#include <hip/hip_runtime.h>
#include <stdint.h>

// Problem constants: n_class=32, n_support=16, n_query=16, D=1024;
// query rows Q = 512. Output (512, 32, 1024) fp32.
constexpr int NC = 32, NS = 16, NQ = 512, D = 1024;
constexpr int QPB = 8;     // queries per block = 4 waves x 2 queries/wave

// clang ext-vectors -> VOP3P packed fp32 (v_pk_fma_f32 etc., full-rate 2xf32)
typedef float v2f __attribute__((ext_vector_type(2)));
typedef float v4f __attribute__((ext_vector_type(4)));

// Packed quad accumulate (round-7 proven): acc += f(t0)+f(t1)+f(t2)+f(t3),
// f(t)=1/(exp2(t)+1), 2 rcp per 4 elements, packed full-rate ops.
// No clamp (validated rounds 3..12): exp2 can't overflow individually for
// this data; if A*B -> inf, rcp -> 0, contribution 0 (truth ~2^-100);
// A+B stays finite so no NaN.
__device__ __forceinline__ void quad_acc(v2f t01, v2f t23, float& acc) {
    v2f A, B;
    A.x = __builtin_amdgcn_exp2f(t01.x);
    A.y = __builtin_amdgcn_exp2f(t01.y);
    B.x = __builtin_amdgcn_exp2f(t23.x);
    B.y = __builtin_amdgcn_exp2f(t23.y);
    A += 1.f;                  // v_pk_add
    B += 1.f;
    v2f prod = A * B;          // v_pk_mul
    v2f sum  = A + B;          // v_pk_add
    acc = fmaf(sum.x, __builtin_amdgcn_rcpf(prod.x), acc);
    acc = fmaf(sum.y, __builtin_amdgcn_rcpf(prod.y), acc);
}

// Direct global->LDS DMA, 16B/lane, zero VGPR round-trip (round-8 proven).
// LDS dest = wave-uniform base + lane*16 (linear); one call = 256 floats.
__device__ __forceinline__ void gload_lds16(const float* g, float* l) {
    __builtin_amdgcn_global_load_lds(
        (const __attribute__((address_space(1))) void*)g,
        (__attribute__((address_space(3))) void*)l,
        16, 0, 0);
}

// Round-13: the three proven components combined.
//   4 x 16KB quarter buffers (64KB), DMA-rotated: score on buf[p] while
//   staging buf[p+1]. After score ALL quarters are resident -> reduction,
//   softmax, proto, stores are BARRIER-FREE and restage-free. 4 barriers
//   total, zero exposed DMA (each covered by a ~700cy score phase),
//   staging costs zero VGPR.
// Ledger rules encoded: (256,2) mandatory — cap 64 spills (R1/R5), uncapped
// halves wave slots (R11: -28us); sc must stay 32 regs (R12: sc[64] spilled);
// queries per-phase not held (R10: held qa/qb fed 40MB of spills);
// sched_barrier between proto quarters stops tail hoisting (R10's spill).
// Tripwire: WRITE_SIZE == 65536 KB exactly, VGPR well under 128.
__global__ __launch_bounds__(256, 2)
void proto_attn_kernel(const float* __restrict__ data, float* __restrict__ out) {
    const int c    = blockIdx.x;   // class
    const int qt   = blockIdx.y;   // query tile
    const int tid  = threadIdx.x;
    const int wave = tid >> 6;
    const int lane = tid & 63;

    // All 4 d-quarters of support[c]: 4 x (16 rows x 256 floats) = 64 KB.
    __shared__ __align__(16) float buf[4][NS * 256];

    const float* sup = data + (size_t)c * NS * D;

    // async-stage quarter p into buf[p]: per wave 4 rows, 1 DMA each (0 VGPR).
    auto stage = [&](int p) {
        #pragma unroll
        for (int r = 0; r < 4; ++r) {
            int row = 4 * wave + r;
            gload_lds16(sup + row * D + p * 256 + lane * 4,
                        &buf[p][row * 256]);
        }
    };

    const float K = 2.88539008177792681472f;   // 2*log2(e); tanh(x)=1-2/(exp2(Kx)+1)
    const int q0 = qt * QPB + wave * 2;
    const v4f* qg0 = reinterpret_cast<const v4f*>(data + (size_t)(NC * NS + q0) * D);
    const v4f* qg1 = qg0 + 256;   // next query row

    stage(0);          // prologue DMA
    __syncthreads();   // bar0: vmcnt drain -> quarter 0 staged

    float sc0[NS], sc1[NS];
    #pragma unroll
    for (int s = 0; s < NS; ++s) { sc0[s] = 0.f; sc1[s] = 0.f; }

    // ---- score phases p=0..3: stage buf[p+1] under compute on buf[p];
    //      barriers after p=0,1,2 only. Queries per-phase (8 regs). ----
    #pragma unroll
    for (int p = 0; p < 4; ++p) {
        if (p < 3) stage(p + 1);
        v4f qA = qg0[(p << 6) + lane] * K;
        v4f qB = qg1[(p << 6) + lane] * K;
        const v4f* B = reinterpret_cast<const v4f*>(buf[p]);
        #pragma unroll
        for (int s = 0; s < NS; ++s) {
            v4f sv = B[(s << 6) + lane];
            quad_acc(sv.xy * qA.xy, sv.zw * qA.zw, sc0[s]);
            quad_acc(sv.xy * qB.xy, sv.zw * qB.zw, sc1[s]);
        }
        if (p < 3) __syncthreads();
    }
    // All 4 quarters resident in LDS. No barriers from here to kernel exit.

    // ---- wave64 butterfly reduction: sc[q][s] = D - 2*sum_d f ----
    #pragma unroll
    for (int s = 0; s < NS; ++s) {
        float r0 = sc0[s], r1 = sc1[s];
        #pragma unroll
        for (int m = 32; m >= 1; m >>= 1) {
            r0 += __shfl_xor(r0, m, 64);
            r1 += __shfl_xor(r1, m, 64);
        }
        sc0[s] = (float)D - 2.f * r0;
        sc1[s] = (float)D - 2.f * r1;
    }

    // ---- softmax over s (16 values, replicated per lane) ----
    const float L2E = 1.44269504088896340736f;
    float m0 = sc0[0], m1 = sc1[0];
    #pragma unroll
    for (int s = 1; s < NS; ++s) { m0 = fmaxf(m0, sc0[s]); m1 = fmaxf(m1, sc1[s]); }
    float sum0 = 0.f, sum1 = 0.f;
    #pragma unroll
    for (int s = 0; s < NS; ++s) {
        sc0[s] = __builtin_amdgcn_exp2f((sc0[s] - m0) * L2E);
        sc1[s] = __builtin_amdgcn_exp2f((sc1[s] - m1) * L2E);
        sum0 += sc0[s];
        sum1 += sc1[s];
    }
    const float inv0 = __builtin_amdgcn_rcpf(sum0);
    const float inv1 = __builtin_amdgcn_rcpf(sum1);
    #pragma unroll
    for (int s = 0; s < NS; ++s) { sc0[s] *= inv0; sc1[s] *= inv1; }

    v4f* og0 = reinterpret_cast<v4f*>(out + ((size_t)q0 * NC + c) * D);
    v4f* og1 = reinterpret_cast<v4f*>(out + ((size_t)(q0 + 1) * NC + c) * D);

    // ---- proto from resident LDS, one quarter at a time; sched_barrier
    //      between quarters keeps live ranges quarter-local (R10 lesson) ----
    #pragma unroll
    for (int p = 0; p < 4; ++p) {
        const v4f* B = reinterpret_cast<const v4f*>(buf[p]);
        v2f oxy0 = 0.f, ozw0 = 0.f, oxy1 = 0.f, ozw1 = 0.f;
        #pragma unroll
        for (int s = 0; s < NS; ++s) {
            v4f sv = B[(s << 6) + lane];
            oxy0 += sv.xy * sc0[s];   // v_pk_fma_f32
            ozw0 += sv.zw * sc0[s];
            oxy1 += sv.xy * sc1[s];
            ozw1 += sv.zw * sc1[s];
        }
        v4f r0, r1;
        r0.xy = oxy0; r0.zw = ozw0;
        r1.xy = oxy1; r1.zw = ozw1;
        og0[(p << 6) + lane] = r0;
        og1[(p << 6) + lane] = r1;
        __builtin_amdgcn_sched_barrier(0);   // no cross-quarter hoisting
    }
}

extern "C" void kernel_launch(void* const* d_in, const int* in_sizes, int n_in,
                              void* d_out, int out_size, void* d_ws, size_t ws_size,
                              hipStream_t stream) {
    (void)in_sizes; (void)n_in; (void)out_size; (void)d_ws; (void)ws_size;
    const float* data = (const float*)d_in[0];
    float* out = (float*)d_out;
    dim3 grid(NC, NQ / QPB);   // 32 classes x 64 query tiles = 2048 blocks
    proto_attn_kernel<<<grid, dim3(256), 0, stream>>>(data, out);
}